// Round 2
// baseline (666.223 us; speedup 1.0000x reference)
//
#include <hip/hip_runtime.h>
#include <cmath>

#define Bq 64
#define Qn 900
#define Tn 100
#define Cn 92
#define INFN 1e9f
#define KSLOT 15   // ceil(900/64) column slots per lane

// ---------------- Kernel A: cost matrix [B,Q,T] (unchanged, verified R0) ----------------
__global__ __launch_bounds__(128) void cost_kernel(
        const float* __restrict__ logits,      // [B,Q,C]
        const float* __restrict__ pred_bbox,   // [B,Q,4]
        const int*   __restrict__ tgt_labels,  // [B,T]
        const float* __restrict__ tgt_bbox,    // [B,T,4]
        float* __restrict__ out_cost)          // [B,Q,T]
{
    const int bq = blockIdx.x;           // b*Q + q
    const int b  = bq / Qn;
    const int t  = threadIdx.x;

    __shared__ float ex[Cn];
    __shared__ float red[128];

    float lg = (t < Cn) ? logits[(size_t)bq * Cn + t] : -3.0e38f;
    red[t] = lg;
    __syncthreads();
    for (int off = 64; off > 0; off >>= 1) {
        if (t < off) red[t] = fmaxf(red[t], red[t + off]);
        __syncthreads();
    }
    float mx = red[0];
    __syncthreads();
    float e = (t < Cn) ? expf(lg - mx) : 0.0f;
    if (t < Cn) ex[t] = e;
    red[t] = e;
    __syncthreads();
    for (int off = 64; off > 0; off >>= 1) {
        if (t < off) red[t] += red[t + off];
        __syncthreads();
    }
    float ssum = red[0];

    if (t < Tn) {
        const float* pb = pred_bbox + (size_t)bq * 4;
        float pcx = pb[0], pcy = pb[1], pw = pb[2], ph = pb[3];
        const float* tb = tgt_bbox + ((size_t)b * Tn + t) * 4;
        float tcx = tb[0], tcy = tb[1], tw = tb[2], th = tb[3];
        int lab = tgt_labels[b * Tn + t];

        float cclass = -(ex[lab] / ssum);
        float cbbox  = fabsf(pcx - tcx) + fabsf(pcy - tcy)
                     + fabsf(pw - tw)  + fabsf(ph - th);

        float px1 = pcx - 0.5f * pw, py1 = pcy - 0.5f * ph;
        float px2 = pcx + 0.5f * pw, py2 = pcy + 0.5f * ph;
        float tx1 = tcx - 0.5f * tw, ty1 = tcy - 0.5f * th;
        float tx2 = tcx + 0.5f * tw, ty2 = tcy + 0.5f * th;

        float a1 = (px2 - px1) * (py2 - py1);
        float a2 = (tx2 - tx1) * (ty2 - ty1);
        float ltx = fmaxf(px1, tx1), lty = fmaxf(py1, ty1);
        float rbx = fminf(px2, tx2), rby = fminf(py2, ty2);
        float iw = fmaxf(rbx - ltx, 0.0f), ih = fmaxf(rby - lty, 0.0f);
        float inter = iw * ih;
        float uni = a1 + a2 - inter;
        float iou = inter / uni;
        float ex1 = fminf(px1, tx1), ey1 = fminf(py1, ty1);
        float ex2 = fmaxf(px2, tx2), ey2 = fmaxf(py2, ty2);
        float ew = fmaxf(ex2 - ex1, 0.0f), eh = fmaxf(ey2 - ey1, 0.0f);
        float ae = ew * eh;
        float giou = iou - (ae - uni) / ae;

        out_cost[(size_t)bq * Tn + t] = cbbox + cclass - giou;
    }
}

// ---------------- Kernel T: transpose cost [B,Q,T] -> costT [B,T,Q] ----------------
// Makes the JV gather (row of cost^T) a coalesced contiguous read.
__global__ __launch_bounds__(256) void transpose_kernel(
        const float* __restrict__ cost,   // [B,Q,T]
        float* __restrict__ costT)        // [B,T,Q]
{
    __shared__ float tile[64][65];        // +1 pad: conflict-free transpose
    const int b  = blockIdx.z;
    const int q0 = blockIdx.x * 64;
    const int t0 = blockIdx.y * 64;
    const int tx = threadIdx.x & 63;
    const int ty = threadIdx.x >> 6;      // 0..3

    const float* cb = cost  + (size_t)b * Qn * Tn;
    float*       ct = costT + (size_t)b * Qn * Tn;

    for (int qq = ty; qq < 64; qq += 4) {
        int q = q0 + qq, t = t0 + tx;
        if (q < Qn && t < Tn) tile[qq][tx] = cb[(size_t)q * Tn + t];
    }
    __syncthreads();
    for (int tt = ty; tt < 64; tt += 4) {
        int t = t0 + tt, q = q0 + tx;
        if (t < Tn && q < Qn) ct[(size_t)t * Qn + q] = tile[tx][tt];
    }
}

// ---------------- Kernel B: wave64-synchronous JV, one wave per batch ----------------
// Column state (v, minv, used) register-resident, statically indexed (full
// unroll); argmin via shuffle butterfly; only p/way/u in LDS. Bit-identical
// arithmetic + first-index tie-break vs the reference.
template<bool TRANS>
__global__ __launch_bounds__(64) void jv_kernel(
        const float* __restrict__ cost,   // TRANS ? [B,T,Q] : [B,Q,T]
        float* __restrict__ out)
{
    const int b    = blockIdx.x;
    const int lane = threadIdx.x;

    __shared__ int   p_lds[Qn + 1];
    __shared__ int   way_lds[Qn + 1];
    __shared__ float u_lds[Tn + 1];
    __shared__ int   qarr[Tn];

    for (int j = lane; j <= Qn; j += 64) { p_lds[j] = 0; way_lds[j] = 0; }
    for (int r = lane; r <= Tn; r += 64) u_lds[r] = 0.0f;
    __syncthreads();

    const float* cb = cost + (size_t)b * Qn * Tn;

    float v_r[KSLOT], minv_r[KSLOT];
    #pragma unroll
    for (int k = 0; k < KSLOT; ++k) v_r[k] = 0.0f;

    for (int i = 0; i < Tn; ++i) {
        if (lane == 0) p_lds[0] = i + 1;
        unsigned used_mask = 0;
        bool used0 = false;
        #pragma unroll
        for (int k = 0; k < KSLOT; ++k) minv_r[k] = INFN;
        __syncthreads();

        int j0 = 0;
        for (int guard = 0; guard < Tn + 4; ++guard) {
            const int i0 = p_lds[j0];            // uniform LDS read
            if (i0 == 0) break;                  // free column found
            // mark j0 used (before scan, matching reference order)
            if (j0 == 0) used0 = true;
            else {
                int c0 = j0 - 1;
                if ((c0 & 63) == lane) used_mask |= (1u << (c0 >> 6));
            }
            const float ui0 = u_lds[i0];
            const float* crow = TRANS ? (cb + (size_t)(i0 - 1) * Qn)
                                      : (cb + (i0 - 1));

            float bestv = 2.0f * INFN;
            int   bestj = 0x7fffffff;
            #pragma unroll
            for (int k = 0; k < KSLOT; ++k) {
                int c = lane + 64 * k;           // 0-based column, j = c+1
                bool valid = (c < Qn) && !((used_mask >> k) & 1u);
                if (valid) {
                    float cur = (TRANS ? crow[c] : crow[(size_t)c * Tn]) - ui0 - v_r[k];
                    if (cur < minv_r[k]) { minv_r[k] = cur; way_lds[c + 1] = j0; }
                    float mv = minv_r[k];
                    if (mv < bestv) { bestv = mv; bestj = c + 1; }  // k asc => j asc: < keeps first
                }
            }
            // 64-lane butterfly argmin, lexicographic (value, then smaller j)
            #pragma unroll
            for (int off = 1; off < 64; off <<= 1) {
                float ov = __shfl_xor(bestv, off);
                int   oj = __shfl_xor(bestj, off);
                if (ov < bestv || (ov == bestv && oj < bestj)) { bestv = ov; bestj = oj; }
            }
            const float delta = bestv;
            // potential updates (reference: u += delta where used; v -= delta
            // where used; minv -= delta where unused)
            if (used0 && lane == 0) u_lds[p_lds[0]] += delta;   // virtual col 0 -> row i+1
            #pragma unroll
            for (int k = 0; k < KSLOT; ++k) {
                int c = lane + 64 * k;
                if (c < Qn) {
                    if ((used_mask >> k) & 1u) {
                        v_r[k] -= delta;
                        int pj = p_lds[c + 1];   // distinct rows across used cols
                        u_lds[pj] += delta;
                    } else {
                        minv_r[k] -= delta;
                    }
                }
            }
            j0 = bestj;
            __syncthreads();                     // u/way visibility for next iter
        }

        // augment along parent pointers (all lanes redundantly, same values)
        {
            int jj = j0;
            while (jj != 0) {
                int j1 = way_lds[jj];
                p_lds[jj] = p_lds[j1];
                jj = j1;
            }
        }
        __syncthreads();
    }

    // q[i] = column (query) assigned to row (target) i
    for (int j = lane + 1; j <= Qn; j += 64) {
        int r = p_lds[j];
        if (r) qarr[r - 1] = j - 1;
    }
    __syncthreads();

    float* out_row = out + (size_t)Bq * Qn * Tn + (size_t)b * Tn;
    float* out_col = out_row + (size_t)Bq * Tn;
    for (int i = lane; i < Tn; i += 64) {
        int qi = qarr[i];
        int rank = 0;
        for (int jj = 0; jj < Tn; ++jj) rank += (qarr[jj] < qi) ? 1 : 0;
        out_row[rank] = (float)qi;   // row_ind: sorted query indices
        out_col[rank] = (float)i;    // col_ind: matched target indices
    }
}

extern "C" void kernel_launch(void* const* d_in, const int* in_sizes, int n_in,
                              void* d_out, int out_size, void* d_ws, size_t ws_size,
                              hipStream_t stream) {
    const float* logits     = (const float*)d_in[0];
    const float* pred_bbox  = (const float*)d_in[1];
    const int*   tgt_labels = (const int*)d_in[2];
    const float* tgt_bbox   = (const float*)d_in[3];
    float* out = (float*)d_out;

    hipLaunchKernelGGL(cost_kernel, dim3(Bq * Qn), dim3(128), 0, stream,
                       logits, pred_bbox, tgt_labels, tgt_bbox, out);

    const size_t needT = (size_t)Bq * Qn * Tn * sizeof(float);
    if (ws_size >= needT) {
        float* costT = (float*)d_ws;
        hipLaunchKernelGGL(transpose_kernel,
                           dim3((Qn + 63) / 64, (Tn + 63) / 64, Bq), dim3(256),
                           0, stream, out, costT);
        hipLaunchKernelGGL((jv_kernel<true>), dim3(Bq), dim3(64), 0, stream,
                           costT, out);
    } else {
        hipLaunchKernelGGL((jv_kernel<false>), dim3(Bq), dim3(64), 0, stream,
                           out, out);
    }
}

// Round 3
// 261.062 us; speedup vs baseline: 2.5520x; 2.5520x over previous
//
#include <hip/hip_runtime.h>
#include <cmath>

#define Bq 64
#define Qn 900
#define Tn 100
#define Cn 92
#define INFN 1e9f
#define NTJ 512   // 8 waves; 2 column slots per thread (900 <= 1024)

// ---------------- Kernel A: cost matrix [B,Q,T] (unchanged, verified) ----------------
__global__ __launch_bounds__(128) void cost_kernel(
        const float* __restrict__ logits,      // [B,Q,C]
        const float* __restrict__ pred_bbox,   // [B,Q,4]
        const int*   __restrict__ tgt_labels,  // [B,T]
        const float* __restrict__ tgt_bbox,    // [B,T,4]
        float* __restrict__ out_cost)          // [B,Q,T]
{
    const int bq = blockIdx.x;
    const int b  = bq / Qn;
    const int t  = threadIdx.x;

    __shared__ float ex[Cn];
    __shared__ float red[128];

    float lg = (t < Cn) ? logits[(size_t)bq * Cn + t] : -3.0e38f;
    red[t] = lg;
    __syncthreads();
    for (int off = 64; off > 0; off >>= 1) {
        if (t < off) red[t] = fmaxf(red[t], red[t + off]);
        __syncthreads();
    }
    float mx = red[0];
    __syncthreads();
    float e = (t < Cn) ? expf(lg - mx) : 0.0f;
    if (t < Cn) ex[t] = e;
    red[t] = e;
    __syncthreads();
    for (int off = 64; off > 0; off >>= 1) {
        if (t < off) red[t] += red[t + off];
        __syncthreads();
    }
    float ssum = red[0];

    if (t < Tn) {
        const float* pb = pred_bbox + (size_t)bq * 4;
        float pcx = pb[0], pcy = pb[1], pw = pb[2], ph = pb[3];
        const float* tb = tgt_bbox + ((size_t)b * Tn + t) * 4;
        float tcx = tb[0], tcy = tb[1], tw = tb[2], th = tb[3];
        int lab = tgt_labels[b * Tn + t];

        float cclass = -(ex[lab] / ssum);
        float cbbox  = fabsf(pcx - tcx) + fabsf(pcy - tcy)
                     + fabsf(pw - tw)  + fabsf(ph - th);

        float px1 = pcx - 0.5f * pw, py1 = pcy - 0.5f * ph;
        float px2 = pcx + 0.5f * pw, py2 = pcy + 0.5f * ph;
        float tx1 = tcx - 0.5f * tw, ty1 = tcy - 0.5f * th;
        float tx2 = tcx + 0.5f * tw, ty2 = tcy + 0.5f * th;

        float a1 = (px2 - px1) * (py2 - py1);
        float a2 = (tx2 - tx1) * (ty2 - ty1);
        float ltx = fmaxf(px1, tx1), lty = fmaxf(py1, ty1);
        float rbx = fminf(px2, tx2), rby = fminf(py2, ty2);
        float iw = fmaxf(rbx - ltx, 0.0f), ih = fmaxf(rby - lty, 0.0f);
        float inter = iw * ih;
        float uni = a1 + a2 - inter;
        float iou = inter / uni;
        float ex1 = fminf(px1, tx1), ey1 = fminf(py1, ty1);
        float ex2 = fmaxf(px2, tx2), ey2 = fmaxf(py2, ty2);
        float ew = fmaxf(ex2 - ex1, 0.0f), eh = fmaxf(ey2 - ey1, 0.0f);
        float ae = ew * eh;
        float giou = iou - (ae - uni) / ae;

        out_cost[(size_t)bq * Tn + t] = cbbox + cclass - giou;
    }
}

// ---------------- Kernel T: transpose cost [B,Q,T] -> costT [B,T,Q] ----------------
__global__ __launch_bounds__(256) void transpose_kernel(
        const float* __restrict__ cost,   // [B,Q,T]
        float* __restrict__ costT)        // [B,T,Q]
{
    __shared__ float tile[64][65];
    const int b  = blockIdx.z;
    const int q0 = blockIdx.x * 64;
    const int t0 = blockIdx.y * 64;
    const int tx = threadIdx.x & 63;
    const int ty = threadIdx.x >> 6;

    const float* cb = cost  + (size_t)b * Qn * Tn;
    float*       ct = costT + (size_t)b * Qn * Tn;

    for (int qq = ty; qq < 64; qq += 4) {
        int q = q0 + qq, t = t0 + tx;
        if (q < Qn && t < Tn) tile[qq][tx] = cb[(size_t)q * Tn + t];
    }
    __syncthreads();
    for (int tt = ty; tt < 64; tt += 4) {
        int t = t0 + tt, q = q0 + tx;
        if (t < Tn && q < Qn) ct[(size_t)t * Qn + q] = tile[tx][tt];
    }
}

// ---------------- Kernel B: 8-wave JV, one block per batch ----------------
// 2 columns per thread in registers; one barrier per inner iteration;
// bit-identical fp sequence + first-index tie-break vs reference.
template<bool TRANS>
__global__ __launch_bounds__(NTJ) void jv_kernel(
        const float* __restrict__ cost,   // TRANS ? [B,T,Q] : [B,Q,T]
        float* __restrict__ out)
{
    const int b    = blockIdx.x;
    const int tid  = threadIdx.x;
    const int lane = tid & 63;
    const int wv   = tid >> 6;            // 0..7

    __shared__ int   p_lds[Qn + 1];
    __shared__ int   way_lds[Qn + 1];
    __shared__ float u_lds[Tn + 1];
    __shared__ float redv[2][8];
    __shared__ int   redj[2][8];
    __shared__ int   qarr[Tn];

    for (int j = tid; j <= Qn; j += NTJ) p_lds[j] = 0;
    if (tid <= Tn) u_lds[tid] = 0.0f;
    __syncthreads();

    const float* cb = cost + (size_t)b * Qn * Tn;

    const int  c0   = tid;               // always < 900
    const int  c1   = tid + NTJ;         // valid iff < 900
    const bool has1 = (c1 < Qn);
    float v0 = 0.0f, v1 = 0.0f;

    for (int i = 0; i < Tn; ++i) {
        if (tid == 0) p_lds[0] = i + 1;
        float minv0 = INFN, minv1 = INFN;
        bool used0c = false, used1c = false;
        __syncthreads();                  // p_lds[0] + prev augment visible

        int j0 = 0;
        int i0 = i + 1;                   // p[0] without an LDS read
        for (int guard = 0; guard < Tn + 2; ++guard) {
            // mark the entering column used (j0 uniform)
            if (j0 > 0) {
                int cc = j0 - 1;
                used0c |= (cc == c0);
                used1c |= (cc == c1);
            }
            const float ui0 = u_lds[i0];                 // uniform broadcast
            const float* crow = TRANS ? (cb + (size_t)(i0 - 1) * Qn)
                                      : (cb + (i0 - 1));
            float cu0 = TRANS ? crow[c0] : crow[(size_t)c0 * Tn];
            float cu1 = 0.0f;
            if (has1) cu1 = TRANS ? crow[c1] : crow[(size_t)c1 * Tn];

            float cur0 = cu0 - ui0 - v0;
            float cur1 = cu1 - ui0 - v1;
            if (!used0c && cur0 < minv0) { minv0 = cur0; way_lds[c0 + 1] = j0; }
            if (has1 && !used1c && cur1 < minv1) { minv1 = cur1; way_lds[c1 + 1] = j0; }

            float m0 = used0c ? INFN : minv0;            // masked, as reference
            float m1 = (has1 && !used1c) ? minv1 : INFN;
            float bv; int bj;
            if (m0 <= m1) { bv = m0; bj = c0 + 1; }      // c0 < c1: <= keeps first
            else          { bv = m1; bj = c1 + 1; }

            #pragma unroll
            for (int off = 1; off < 64; off <<= 1) {     // wave argmin, lexicographic
                float ov = __shfl_xor(bv, off);
                int   oj = __shfl_xor(bj, off);
                if (ov < bv || (ov == bv && oj < bj)) { bv = ov; bj = oj; }
            }
            const int par = guard & 1;                   // double-buffered reduce slots
            if (lane == 0) { redv[par][wv] = bv; redj[par][wv] = bj; }
            __syncthreads();

            float delta = redv[par][0]; int bestj = redj[par][0];
            #pragma unroll
            for (int w = 1; w < 8; ++w) {
                float ov = redv[par][w]; int oj = redj[par][w];
                if (ov < delta || (ov == delta && oj < bestj)) { delta = ov; bestj = oj; }
            }
            int bp = p_lds[bestj];                       // issued early; uniform

            // potential updates — identical fp order to reference
            if (tid == 0) u_lds[i + 1] += delta;         // virtual col 0 -> root row
            if (used0c) {
                v0 -= delta;
                int pj = p_lds[c0 + 1];
                u_lds[pj] += delta;                      // distinct rows: no races
            } else {
                minv0 -= delta;
            }
            if (has1) {
                if (used1c) {
                    v1 -= delta;
                    int pj = p_lds[c1 + 1];
                    u_lds[pj] += delta;
                } else {
                    minv1 -= delta;
                }
            }

            j0 = bestj; i0 = bp;
            if (i0 == 0) break;                          // uniform exit
        }

        if (tid == 0) {                                  // augment (short chase)
            int jj = j0;
            while (jj != 0) { int j1 = way_lds[jj]; p_lds[jj] = p_lds[j1]; jj = j1; }
        }
        __syncthreads();
    }

    for (int j = tid + 1; j <= Qn; j += NTJ) {
        int r = p_lds[j];
        if (r) qarr[r - 1] = j - 1;
    }
    __syncthreads();

    float* out_row = out + (size_t)Bq * Qn * Tn + (size_t)b * Tn;
    float* out_col = out_row + (size_t)Bq * Tn;
    for (int i = tid; i < Tn; i += NTJ) {
        int qi = qarr[i];
        int rank = 0;
        for (int jj = 0; jj < Tn; ++jj) rank += (qarr[jj] < qi) ? 1 : 0;
        out_row[rank] = (float)qi;   // row_ind: sorted query indices
        out_col[rank] = (float)i;    // col_ind: matched target indices
    }
}

extern "C" void kernel_launch(void* const* d_in, const int* in_sizes, int n_in,
                              void* d_out, int out_size, void* d_ws, size_t ws_size,
                              hipStream_t stream) {
    const float* logits     = (const float*)d_in[0];
    const float* pred_bbox  = (const float*)d_in[1];
    const int*   tgt_labels = (const int*)d_in[2];
    const float* tgt_bbox   = (const float*)d_in[3];
    float* out = (float*)d_out;

    hipLaunchKernelGGL(cost_kernel, dim3(Bq * Qn), dim3(128), 0, stream,
                       logits, pred_bbox, tgt_labels, tgt_bbox, out);

    const size_t needT = (size_t)Bq * Qn * Tn * sizeof(float);
    if (ws_size >= needT) {
        float* costT = (float*)d_ws;
        hipLaunchKernelGGL(transpose_kernel,
                           dim3((Qn + 63) / 64, (Tn + 63) / 64, Bq), dim3(256),
                           0, stream, out, costT);
        hipLaunchKernelGGL((jv_kernel<true>), dim3(Bq), dim3(NTJ), 0, stream,
                           costT, out);
    } else {
        hipLaunchKernelGGL((jv_kernel<false>), dim3(Bq), dim3(NTJ), 0, stream,
                           out, out);
    }
}

// Round 4
// 227.575 us; speedup vs baseline: 2.9275x; 1.1471x over previous
//
#include <hip/hip_runtime.h>
#include <cmath>

#define Bq 64
#define Qn 900
#define Tn 100
#define Cn 92
#define INFN 1e9f
#define QT 64         // queries per cost tile
#define NQT 15        // ceil(900/64)
#define NTJ 256       // jv: 4 waves; thread t owns columns 4t..4t+3 (t<225)

// ---------------- Kernel A: fused cost + transpose ----------------
// One block per (64-query tile, batch). Writes cost [B,Q,T] and costT [B,T,Q],
// both coalesced. Replaces the R2 cost_kernel + transpose_kernel pair.
__global__ __launch_bounds__(256) void cost_fused_kernel(
        const float* __restrict__ logits,      // [B,Q,C]
        const float* __restrict__ pred_bbox,   // [B,Q,4]
        const int*   __restrict__ tgt_labels,  // [B,T]
        const float* __restrict__ tgt_bbox,    // [B,T,4]
        float* __restrict__ cost,              // [B,Q,T]
        float* __restrict__ costT)             // [B,T,Q] (may be null)
{
    const int b   = blockIdx.y;
    const int q0  = blockIdx.x * QT;
    const int nq  = (q0 + QT <= Qn) ? QT : (Qn - q0);   // 64, or 4 on last tile
    const int tid = threadIdx.x;

    __shared__ float prob[QT * Cn];        // logits, then softmax probs
    __shared__ float pb_s[QT][4];
    __shared__ float tb_s[Tn][4];
    __shared__ int   lab_s[Tn];
    __shared__ float ctile[QT][Tn + 1];    // +1 pad: conflict-free col reads

    const float* lg_src = logits + ((size_t)b * Qn + q0) * Cn;
    for (int idx = tid; idx < nq * Cn; idx += 256) prob[idx] = lg_src[idx];
    for (int idx = tid; idx < nq * 4; idx += 256)
        ((float*)pb_s)[idx] = pred_bbox[((size_t)b * Qn + q0) * 4 + idx];
    for (int idx = tid; idx < Tn * 4; idx += 256)
        ((float*)tb_s)[idx] = tgt_bbox[(size_t)b * Tn * 4 + idx];
    for (int idx = tid; idx < Tn; idx += 256)
        lab_s[idx] = tgt_labels[b * Tn + idx];
    __syncthreads();

    // softmax per query: 4 lanes per query (64 groups exactly cover QT=64)
    const int g = tid >> 2, l4 = tid & 3;
    if (g < nq) {
        float mx = -3.0e38f;
        for (int c = l4; c < Cn; c += 4) mx = fmaxf(mx, prob[g * Cn + c]);
        mx = fmaxf(mx, __shfl_xor(mx, 1));
        mx = fmaxf(mx, __shfl_xor(mx, 2));
        float s = 0.0f;
        for (int c = l4; c < Cn; c += 4) s += expf(prob[g * Cn + c] - mx);
        s += __shfl_xor(s, 1);
        s += __shfl_xor(s, 2);
        float inv = 1.0f / s;
        for (int c = l4; c < Cn; c += 4)
            prob[g * Cn + c] = expf(prob[g * Cn + c] - mx) * inv;
    }
    __syncthreads();

    const int total = nq * Tn;
    float* cdst = cost + (size_t)b * Qn * Tn + (size_t)q0 * Tn;
    for (int flat = tid; flat < total; flat += 256) {
        int q = flat / Tn, tt = flat - q * Tn;
        float pcx = pb_s[q][0], pcy = pb_s[q][1], pw = pb_s[q][2], ph = pb_s[q][3];
        float tcx = tb_s[tt][0], tcy = tb_s[tt][1], tw = tb_s[tt][2], th = tb_s[tt][3];

        float cclass = -prob[q * Cn + lab_s[tt]];
        float cbbox  = fabsf(pcx - tcx) + fabsf(pcy - tcy)
                     + fabsf(pw - tw)  + fabsf(ph - th);

        float px1 = pcx - 0.5f * pw, py1 = pcy - 0.5f * ph;
        float px2 = pcx + 0.5f * pw, py2 = pcy + 0.5f * ph;
        float tx1 = tcx - 0.5f * tw, ty1 = tcy - 0.5f * th;
        float tx2 = tcx + 0.5f * tw, ty2 = tcy + 0.5f * th;

        float a1 = (px2 - px1) * (py2 - py1);
        float a2 = (tx2 - tx1) * (ty2 - ty1);
        float iw = fmaxf(fminf(px2, tx2) - fmaxf(px1, tx1), 0.0f);
        float ih = fmaxf(fminf(py2, ty2) - fmaxf(py1, ty1), 0.0f);
        float inter = iw * ih;
        float uni = a1 + a2 - inter;
        float iou = inter / uni;
        float ew = fmaxf(fmaxf(px2, tx2) - fminf(px1, tx1), 0.0f);
        float eh = fmaxf(fmaxf(py2, ty2) - fminf(py1, ty1), 0.0f);
        float ae = ew * eh;
        float val = cbbox + cclass - (iou - (ae - uni) / ae);

        cdst[flat] = val;                 // coalesced [B,Q,T] write
        ctile[q][tt] = val;
    }
    if (costT) {
        __syncthreads();
        float* tdst = costT + (size_t)b * Qn * Tn + q0;
        if (nq == QT) {
            for (int flat = tid; flat < QT * Tn; flat += 256) {
                int r = flat >> 6, c = flat & 63;
                tdst[(size_t)r * Qn + c] = ctile[c][r];   // coalesced 256B rows
            }
        } else {
            for (int flat = tid; flat < nq * Tn; flat += 256) {
                int r = flat / nq, c = flat - r * nq;
                tdst[(size_t)r * Qn + c] = ctile[c][r];
            }
        }
    }
}

// ---------------- Kernel B: 4-wave JV with software-pipelined row loads ----
// Thread t (t<225) owns columns 4t..4t+3 (one dwordx4 per row). v/minv/used in
// registers; one barrier per inner iteration + one per search. Next row's cost
// + u are prefetched right after the reduce, hiding load latency under the
// update sweep (exact: row bp is not in the tree, so u[bp] is unmodified).
// Bit-identical fp sequence + first-index tie-break vs the reference.
template<bool TRANS>
__global__ __launch_bounds__(NTJ) void jv_kernel(
        const float* __restrict__ cost,   // TRANS ? [B,T,Q] : [B,Q,T]
        float* __restrict__ out)
{
    const int b    = blockIdx.x;
    const int tid  = threadIdx.x;
    const int lane = tid & 63;
    const int wv   = tid >> 6;            // 0..3
    const bool act = (tid < Qn / 4);      // 225 threads cover 900 columns

    __shared__ int   p_lds[Qn + 1];
    __shared__ int   way_lds[Qn + 1];
    __shared__ float u_lds[Tn + 1];
    __shared__ float redv[2][4];
    __shared__ int   redj[2][4];
    __shared__ int   qarr[Tn];

    for (int j = tid; j <= Qn; j += NTJ) p_lds[j] = 0;
    if (tid <= Tn) u_lds[tid] = 0.0f;
    __syncthreads();

    const float* cb = cost + (size_t)b * Qn * Tn;
    const int cbase = 4 * tid;            // first owned 0-based column

    float varr[4] = {0.0f, 0.0f, 0.0f, 0.0f};

    for (int i = 0; i < Tn; ++i) {
        float minv[4] = {INFN, INFN, INFN, INFN};
        unsigned um = 0;                  // per-slot used bits
        int i0 = i + 1, j0 = 0;
        if (tid == 0) p_lds[0] = i0;      // only read by tid 0's augment

        // prologue prefetch: row i (cost) + u[i+1] (always 0, race-free)
        float c0v = 0, c1v = 0, c2v = 0, c3v = 0;
        if (act) {
            if (TRANS) {
                float4 cr = *(const float4*)(cb + (size_t)(i0 - 1) * Qn + cbase);
                c0v = cr.x; c1v = cr.y; c2v = cr.z; c3v = cr.w;
            } else {
                const float* cp = cb + (i0 - 1);
                c0v = cp[(size_t)cbase * Tn];       c1v = cp[(size_t)(cbase + 1) * Tn];
                c2v = cp[(size_t)(cbase + 2) * Tn]; c3v = cp[(size_t)(cbase + 3) * Tn];
            }
        }
        float ui0 = u_lds[i0];

        for (int it = 0; it < Tn + 2; ++it) {
            // mark entering column used (j0 uniform; root handled separately)
            if (j0 > 0 && act) {
                int cc = j0 - 1;
                if ((cc >> 2) == tid) um |= 1u << (cc & 3);
            }
            // scan owned columns (reference: cur = cost - u[i0] - v, masked)
            float bv = 3.0e9f; int bj = 0x3fffffff;
            if (act) {
                float crr[4] = {c0v, c1v, c2v, c3v};
                #pragma unroll
                for (int k = 0; k < 4; ++k) {
                    if (!((um >> k) & 1u)) {
                        float cur = crr[k] - ui0 - varr[k];
                        if (cur < minv[k]) { minv[k] = cur; way_lds[cbase + k + 1] = j0; }
                        if (minv[k] < bv) { bv = minv[k]; bj = cbase + k + 1; }
                    }
                }
            }
            // 64-lane lexicographic argmin
            #pragma unroll
            for (int off = 1; off < 64; off <<= 1) {
                float ov = __shfl_xor(bv, off);
                int   oj = __shfl_xor(bj, off);
                if (ov < bv || (ov == bv && oj < bj)) { bv = ov; bj = oj; }
            }
            const int par = it & 1;       // double-buffered reduce slots
            if (lane == 0) { redv[par][wv] = bv; redj[par][wv] = bj; }
            __syncthreads();
            float delta = redv[par][0]; int bestj = redj[par][0];
            #pragma unroll
            for (int w = 1; w < 4; ++w) {
                float ov = redv[par][w]; int oj = redj[par][w];
                if (ov < delta || (ov == delta && oj < bestj)) { delta = ov; bestj = oj; }
            }
            const int bp = p_lds[bestj];  // uniform; p stable during search

            // prefetch next row + u[bp] BEFORE the update sweep (exact: bp
            // is not in the tree, so u[bp] is untouched by this iteration)
            float ui_n = 0.0f, n0 = 0, n1 = 0, n2 = 0, n3 = 0;
            if (bp != 0) {
                if (act) {
                    if (TRANS) {
                        float4 cr = *(const float4*)(cb + (size_t)(bp - 1) * Qn + cbase);
                        n0 = cr.x; n1 = cr.y; n2 = cr.z; n3 = cr.w;
                    } else {
                        const float* cp = cb + (bp - 1);
                        n0 = cp[(size_t)cbase * Tn];       n1 = cp[(size_t)(cbase + 1) * Tn];
                        n2 = cp[(size_t)(cbase + 2) * Tn]; n3 = cp[(size_t)(cbase + 3) * Tn];
                    }
                }
                ui_n = u_lds[bp];
            }

            // potential updates — identical fp order to reference
            if (tid == 0) u_lds[i + 1] += delta;     // virtual col 0 -> root row
            if (act) {
                #pragma unroll
                for (int k = 0; k < 4; ++k) {
                    if ((um >> k) & 1u) {
                        varr[k] -= delta;
                        u_lds[p_lds[cbase + k + 1]] += delta;  // distinct rows
                    } else {
                        minv[k] -= delta;
                    }
                }
            }
            j0 = bestj;
            if (bp == 0) break;           // uniform exit: free column found
            i0 = bp; ui0 = ui_n;
            c0v = n0; c1v = n1; c2v = n2; c3v = n3;
        }

        if (tid == 0) {                   // augment along parent pointers
            int jj = j0;
            while (jj != 0) { int j1 = way_lds[jj]; p_lds[jj] = p_lds[j1]; jj = j1; }
        }
        __syncthreads();                  // protects way/p vs next search
    }

    for (int j = tid + 1; j <= Qn; j += NTJ) {
        int r = p_lds[j];
        if (r) qarr[r - 1] = j - 1;
    }
    __syncthreads();

    float* out_row = out + (size_t)Bq * Qn * Tn + (size_t)b * Tn;
    float* out_col = out_row + (size_t)Bq * Tn;
    for (int i = tid; i < Tn; i += NTJ) {
        int qi = qarr[i];
        int rank = 0;
        for (int jj = 0; jj < Tn; ++jj) rank += (qarr[jj] < qi) ? 1 : 0;
        out_row[rank] = (float)qi;   // row_ind: sorted query indices
        out_col[rank] = (float)i;    // col_ind: matched target indices
    }
}

extern "C" void kernel_launch(void* const* d_in, const int* in_sizes, int n_in,
                              void* d_out, int out_size, void* d_ws, size_t ws_size,
                              hipStream_t stream) {
    const float* logits     = (const float*)d_in[0];
    const float* pred_bbox  = (const float*)d_in[1];
    const int*   tgt_labels = (const int*)d_in[2];
    const float* tgt_bbox   = (const float*)d_in[3];
    float* out = (float*)d_out;

    const size_t needT = (size_t)Bq * Qn * Tn * sizeof(float);
    float* costT = (ws_size >= needT) ? (float*)d_ws : nullptr;

    hipLaunchKernelGGL(cost_fused_kernel, dim3(NQT, Bq), dim3(256), 0, stream,
                       logits, pred_bbox, tgt_labels, tgt_bbox, out, costT);
    if (costT) {
        hipLaunchKernelGGL((jv_kernel<true>), dim3(Bq), dim3(NTJ), 0, stream,
                           costT, out);
    } else {
        hipLaunchKernelGGL((jv_kernel<false>), dim3(Bq), dim3(NTJ), 0, stream,
                           out, out);
    }
}

// Round 5
// 106.246 us; speedup vs baseline: 6.2706x; 2.1420x over previous
//
#include <hip/hip_runtime.h>
#include <cmath>

#define Bq 64
#define Qn 900
#define Tn 100
#define Cn 92
#define INFN 1e9f
#define QT 64         // queries per cost tile
#define NQT 15        // ceil(900/64)
#define NTJ 256       // jv: 4 waves; thread t owns columns 4t..4t+3 (t<225)

// ---------------- Kernel A: fused cost + transpose (unchanged, verified R3) ----------------
__global__ __launch_bounds__(256) void cost_fused_kernel(
        const float* __restrict__ logits,      // [B,Q,C]
        const float* __restrict__ pred_bbox,   // [B,Q,4]
        const int*   __restrict__ tgt_labels,  // [B,T]
        const float* __restrict__ tgt_bbox,    // [B,T,4]
        float* __restrict__ cost,              // [B,Q,T]
        float* __restrict__ costT)             // [B,T,Q] (may be null)
{
    const int b   = blockIdx.y;
    const int q0  = blockIdx.x * QT;
    const int nq  = (q0 + QT <= Qn) ? QT : (Qn - q0);
    const int tid = threadIdx.x;

    __shared__ float prob[QT * Cn];
    __shared__ float pb_s[QT][4];
    __shared__ float tb_s[Tn][4];
    __shared__ int   lab_s[Tn];
    __shared__ float ctile[QT][Tn + 1];

    const float* lg_src = logits + ((size_t)b * Qn + q0) * Cn;
    for (int idx = tid; idx < nq * Cn; idx += 256) prob[idx] = lg_src[idx];
    for (int idx = tid; idx < nq * 4; idx += 256)
        ((float*)pb_s)[idx] = pred_bbox[((size_t)b * Qn + q0) * 4 + idx];
    for (int idx = tid; idx < Tn * 4; idx += 256)
        ((float*)tb_s)[idx] = tgt_bbox[(size_t)b * Tn * 4 + idx];
    for (int idx = tid; idx < Tn; idx += 256)
        lab_s[idx] = tgt_labels[b * Tn + idx];
    __syncthreads();

    const int g = tid >> 2, l4 = tid & 3;
    if (g < nq) {
        float mx = -3.0e38f;
        for (int c = l4; c < Cn; c += 4) mx = fmaxf(mx, prob[g * Cn + c]);
        mx = fmaxf(mx, __shfl_xor(mx, 1));
        mx = fmaxf(mx, __shfl_xor(mx, 2));
        float s = 0.0f;
        for (int c = l4; c < Cn; c += 4) s += expf(prob[g * Cn + c] - mx);
        s += __shfl_xor(s, 1);
        s += __shfl_xor(s, 2);
        float inv = 1.0f / s;
        for (int c = l4; c < Cn; c += 4)
            prob[g * Cn + c] = expf(prob[g * Cn + c] - mx) * inv;
    }
    __syncthreads();

    const int total = nq * Tn;
    float* cdst = cost + (size_t)b * Qn * Tn + (size_t)q0 * Tn;
    for (int flat = tid; flat < total; flat += 256) {
        int q = flat / Tn, tt = flat - q * Tn;
        float pcx = pb_s[q][0], pcy = pb_s[q][1], pw = pb_s[q][2], ph = pb_s[q][3];
        float tcx = tb_s[tt][0], tcy = tb_s[tt][1], tw = tb_s[tt][2], th = tb_s[tt][3];

        float cclass = -prob[q * Cn + lab_s[tt]];
        float cbbox  = fabsf(pcx - tcx) + fabsf(pcy - tcy)
                     + fabsf(pw - tw)  + fabsf(ph - th);

        float px1 = pcx - 0.5f * pw, py1 = pcy - 0.5f * ph;
        float px2 = pcx + 0.5f * pw, py2 = pcy + 0.5f * ph;
        float tx1 = tcx - 0.5f * tw, ty1 = tcy - 0.5f * th;
        float tx2 = tcx + 0.5f * tw, ty2 = tcy + 0.5f * th;

        float a1 = (px2 - px1) * (py2 - py1);
        float a2 = (tx2 - tx1) * (ty2 - ty1);
        float iw = fmaxf(fminf(px2, tx2) - fmaxf(px1, tx1), 0.0f);
        float ih = fmaxf(fminf(py2, ty2) - fmaxf(py1, ty1), 0.0f);
        float inter = iw * ih;
        float uni = a1 + a2 - inter;
        float iou = inter / uni;
        float ew = fmaxf(fmaxf(px2, tx2) - fminf(px1, tx1), 0.0f);
        float eh = fmaxf(fmaxf(py2, ty2) - fminf(py1, ty1), 0.0f);
        float ae = ew * eh;
        float val = cbbox + cclass - (iou - (ae - uni) / ae);

        cdst[flat] = val;
        ctile[q][tt] = val;
    }
    if (costT) {
        __syncthreads();
        float* tdst = costT + (size_t)b * Qn * Tn + q0;
        if (nq == QT) {
            for (int flat = tid; flat < QT * Tn; flat += 256) {
                int r = flat >> 6, c = flat & 63;
                tdst[(size_t)r * Qn + c] = ctile[c][r];
            }
        } else {
            for (int flat = tid; flat < nq * Tn; flat += 256) {
                int r = flat / nq, c = flat - r * nq;
                tdst[(size_t)r * Qn + c] = ctile[c][r];
            }
        }
    }
}

// ---------------- Kernel B: JV with greedy dual initialization ----------------
// Phase 0: u[i] = min_j cost[i][j] (+argmin), v = 0  -> feasible duals.
// Phase 1: greedy-assign rows to their argmin column (atomicCAS; reduced cost
//          0 at argmin, so complementary slackness holds for any winner).
// Phase 2: augmenting-path searches (R3 machinery) ONLY for conflicted rows.
// Any feasible start converges to the exact optimum, which is unique a.s. and
// therefore identical to the reference's assignment.
template<bool TRANS>
__global__ __launch_bounds__(NTJ) void jv_kernel(
        const float* __restrict__ cost,   // TRANS ? [B,T,Q] : [B,Q,T]
        float* __restrict__ out)
{
    const int b    = blockIdx.x;
    const int tid  = threadIdx.x;
    const int lane = tid & 63;
    const int wv   = tid >> 6;            // 0..3
    const bool act = (tid < Qn / 4);      // 225 threads cover 900 columns

    __shared__ int   p_lds[Qn + 1];
    __shared__ int   way_lds[Qn + 1];
    __shared__ float u_lds[Tn + 1];
    __shared__ int   amin_lds[Tn];
    __shared__ unsigned char asg[Tn];
    __shared__ int   freelist[Tn];
    __shared__ int   nfree_s;
    __shared__ float redv[2][4];
    __shared__ int   redj[2][4];
    __shared__ int   qarr[Tn];

    for (int j = tid; j <= Qn; j += NTJ) p_lds[j] = 0;
    if (tid == 0) nfree_s = 0;
    __syncthreads();

    const float* cb = cost + (size_t)b * Qn * Tn;

    // ---- phase 0: per-row min + argmin (wave per row, coalesced on costT) ----
    for (int r = wv; r < Tn; r += 4) {
        float bv = 3.0e38f; int bj = 0x3fffffff;
        #pragma unroll
        for (int k = 0; k < 15; ++k) {
            int c = lane + 64 * k;
            if (c < Qn) {
                float x = TRANS ? cb[(size_t)r * Qn + c] : cb[(size_t)c * Tn + r];
                if (x < bv) { bv = x; bj = c; }   // k asc: keeps first
            }
        }
        #pragma unroll
        for (int off = 1; off < 64; off <<= 1) {
            float ov = __shfl_xor(bv, off);
            int   oj = __shfl_xor(bj, off);
            if (ov < bv || (ov == bv && oj < bj)) { bv = ov; bj = oj; }
        }
        if (lane == 0) { u_lds[r + 1] = bv; amin_lds[r] = bj; }
    }
    __syncthreads();

    // ---- phase 1: greedy assignment (any winner preserves CS) ----
    if (tid < Tn) {
        int j = amin_lds[tid];
        int old = atomicCAS(&p_lds[j + 1], 0, tid + 1);
        asg[tid] = (old == 0) ? 1 : 0;
    }
    __syncthreads();
    if (tid < Tn && !asg[tid]) {
        int s = atomicAdd(&nfree_s, 1);
        freelist[s] = tid;                // order irrelevant
    }
    __syncthreads();
    const int nfree = nfree_s;

    // ---- phase 2: augmenting searches for conflicted rows ----
    const int cbase = 4 * tid;
    float varr[4] = {0.0f, 0.0f, 0.0f, 0.0f};

    for (int s = 0; s < nfree; ++s) {
        const int ri = freelist[s];
        float minv[4] = {INFN, INFN, INFN, INFN};
        unsigned um = 0;
        int i0 = ri + 1, j0 = 0;
        if (tid == 0) p_lds[0] = i0;      // only tid0's augment reads it

        float c0v = 0, c1v = 0, c2v = 0, c3v = 0;
        if (act) {
            if (TRANS) {
                float4 cr = *(const float4*)(cb + (size_t)(i0 - 1) * Qn + cbase);
                c0v = cr.x; c1v = cr.y; c2v = cr.z; c3v = cr.w;
            } else {
                const float* cp = cb + (i0 - 1);
                c0v = cp[(size_t)cbase * Tn];       c1v = cp[(size_t)(cbase + 1) * Tn];
                c2v = cp[(size_t)(cbase + 2) * Tn]; c3v = cp[(size_t)(cbase + 3) * Tn];
            }
        }
        float ui0 = u_lds[i0];

        for (int it = 0; it < Tn + 2; ++it) {
            if (j0 > 0 && act) {
                int cc = j0 - 1;
                if ((cc >> 2) == tid) um |= 1u << (cc & 3);
            }
            float bv = 3.0e9f; int bj = 0x3fffffff;
            if (act) {
                float crr[4] = {c0v, c1v, c2v, c3v};
                #pragma unroll
                for (int k = 0; k < 4; ++k) {
                    if (!((um >> k) & 1u)) {
                        float cur = crr[k] - ui0 - varr[k];
                        if (cur < minv[k]) { minv[k] = cur; way_lds[cbase + k + 1] = j0; }
                        if (minv[k] < bv) { bv = minv[k]; bj = cbase + k + 1; }
                    }
                }
            }
            #pragma unroll
            for (int off = 1; off < 64; off <<= 1) {
                float ov = __shfl_xor(bv, off);
                int   oj = __shfl_xor(bj, off);
                if (ov < bv || (ov == bv && oj < bj)) { bv = ov; bj = oj; }
            }
            const int par = it & 1;
            if (lane == 0) { redv[par][wv] = bv; redj[par][wv] = bj; }
            __syncthreads();
            float delta = redv[par][0]; int bestj = redj[par][0];
            #pragma unroll
            for (int w = 1; w < 4; ++w) {
                float ov = redv[par][w]; int oj = redj[par][w];
                if (ov < delta || (ov == delta && oj < bestj)) { delta = ov; bestj = oj; }
            }
            const int bp = p_lds[bestj];

            // prefetch next row + u[bp] (row bp not in tree: u[bp] unmodified)
            float ui_n = 0.0f, n0 = 0, n1 = 0, n2 = 0, n3 = 0;
            if (bp != 0) {
                if (act) {
                    if (TRANS) {
                        float4 cr = *(const float4*)(cb + (size_t)(bp - 1) * Qn + cbase);
                        n0 = cr.x; n1 = cr.y; n2 = cr.z; n3 = cr.w;
                    } else {
                        const float* cp = cb + (bp - 1);
                        n0 = cp[(size_t)cbase * Tn];       n1 = cp[(size_t)(cbase + 1) * Tn];
                        n2 = cp[(size_t)(cbase + 2) * Tn]; n3 = cp[(size_t)(cbase + 3) * Tn];
                    }
                }
                ui_n = u_lds[bp];
            }

            if (tid == 0) u_lds[ri + 1] += delta;    // root row (virtual col 0)
            if (act) {
                #pragma unroll
                for (int k = 0; k < 4; ++k) {
                    if ((um >> k) & 1u) {
                        varr[k] -= delta;
                        u_lds[p_lds[cbase + k + 1]] += delta;  // distinct rows
                    } else {
                        minv[k] -= delta;
                    }
                }
            }
            j0 = bestj;
            if (bp == 0) break;
            i0 = bp; ui0 = ui_n;
            c0v = n0; c1v = n1; c2v = n2; c3v = n3;
        }

        if (tid == 0) {                   // augment along parent pointers
            int jj = j0;
            while (jj != 0) { int j1 = way_lds[jj]; p_lds[jj] = p_lds[j1]; jj = j1; }
        }
        __syncthreads();
    }

    // ---- output ----
    for (int j = tid + 1; j <= Qn; j += NTJ) {
        int r = p_lds[j];
        if (r) qarr[r - 1] = j - 1;
    }
    __syncthreads();

    float* out_row = out + (size_t)Bq * Qn * Tn + (size_t)b * Tn;
    float* out_col = out_row + (size_t)Bq * Tn;
    for (int i = tid; i < Tn; i += NTJ) {
        int qi = qarr[i];
        int rank = 0;
        for (int jj = 0; jj < Tn; ++jj) rank += (qarr[jj] < qi) ? 1 : 0;
        out_row[rank] = (float)qi;   // row_ind: sorted query indices
        out_col[rank] = (float)i;    // col_ind: matched target indices
    }
}

extern "C" void kernel_launch(void* const* d_in, const int* in_sizes, int n_in,
                              void* d_out, int out_size, void* d_ws, size_t ws_size,
                              hipStream_t stream) {
    const float* logits     = (const float*)d_in[0];
    const float* pred_bbox  = (const float*)d_in[1];
    const int*   tgt_labels = (const int*)d_in[2];
    const float* tgt_bbox   = (const float*)d_in[3];
    float* out = (float*)d_out;

    const size_t needT = (size_t)Bq * Qn * Tn * sizeof(float);
    float* costT = (ws_size >= needT) ? (float*)d_ws : nullptr;

    hipLaunchKernelGGL(cost_fused_kernel, dim3(NQT, Bq), dim3(256), 0, stream,
                       logits, pred_bbox, tgt_labels, tgt_bbox, out, costT);
    if (costT) {
        hipLaunchKernelGGL((jv_kernel<true>), dim3(Bq), dim3(NTJ), 0, stream,
                           costT, out);
    } else {
        hipLaunchKernelGGL((jv_kernel<false>), dim3(Bq), dim3(NTJ), 0, stream,
                           out, out);
    }
}